// Round 1
// baseline (339.444 us; speedup 1.0000x reference)
//
#include <hip/hip_runtime.h>
#include <hip/hip_bf16.h>

#define B_  8
#define F_  256
#define N_  4096
#define BN  32
#define COLS 96       // 3*BN
#define BK  32
#define CHUNKS 8      // F_/BK
#define PAD 40        // BK + 8 -> row stride 80B = 20 dwords, breaks pow2 bank stride
#define THREADS 256

typedef __attribute__((ext_vector_type(8))) short short8;
typedef __attribute__((ext_vector_type(4))) float f32x4;

__device__ inline unsigned short f2bf(float f) {
    union { float f; unsigned int u; } c; c.f = f;
    unsigned int u = c.u;
    // round-to-nearest-even bf16
    unsigned int r = u + 0x7FFFu + ((u >> 16) & 1u);
    return (unsigned short)(r >> 16);
}

__global__ __launch_bounds__(THREADS, 2) void lie_fused_kernel(
    const float* __restrict__ x, const float* __restrict__ M1,
    const float* __restrict__ M2, const float* __restrict__ W1,
    const float* __restrict__ W2, float* __restrict__ out)
{
    // LDS: W slices [weight][g][f_local], X tile [col][f_local]; both f-contiguous
    __shared__ unsigned short Ws[2][F_][PAD];   // 40960 B
    __shared__ unsigned short Xs[COLS][PAD];    //  7680 B

    const int tid  = threadIdx.x;
    const int wave = tid >> 6;
    const int lane = tid & 63;
    const int c16  = lane & 15;
    const int quad = lane >> 4;

    const int bid   = blockIdx.x;
    const int b     = bid >> 7;      // /128 n-tiles
    const int ntile = bid & 127;
    const int n0    = ntile * BN;

    // acc[w_id][gt][ct]: wave owns g in [wave*64, wave*64+64), all 6 col-tiles
    f32x4 acc[2][4][6];
    #pragma unroll
    for (int wi = 0; wi < 2; wi++)
        #pragma unroll
        for (int gt = 0; gt < 4; gt++)
            #pragma unroll
            for (int ct = 0; ct < 6; ct++)
                acc[wi][gt][ct] = (f32x4)(0.f);

    for (int ch = 0; ch < CHUNKS; ch++) {
        const int fb = ch * BK;

        // ---- stage W1,W2 chunk: 2*256*32 fp32 -> bf16 LDS (64 elems = 16 float4 / thread)
        #pragma unroll
        for (int i = 0; i < 16; i++) {
            int idx = tid + THREADS * i;          // 0..4095
            int rem = idx & 2047;
            int g   = rem >> 3;
            int q   = rem & 7;
            const float* wp = (idx & 2048) ? W2 : W1;
            const float4 v = *(const float4*)(wp + g * F_ + fb + q * 4);
            unsigned long long pk =
                  (unsigned long long)f2bf(v.x)
                | ((unsigned long long)f2bf(v.y) << 16)
                | ((unsigned long long)f2bf(v.z) << 32)
                | ((unsigned long long)f2bf(v.w) << 48);
            *(unsigned long long*)&Ws[(idx >> 11)][g][q * 4] = pk;
        }

        // ---- stage X chunk: 96 rows(f,k) x 32 n fp32 -> bf16 LDS transposed (3 float4 / thread)
        #pragma unroll
        for (int i = 0; i < 3; i++) {
            int idx = tid + THREADS * i;          // 0..767
            int row = idx >> 3;                   // 0..95 = fl*3 + k
            int q   = idx & 7;
            int fl  = row / 3;
            int k   = row - fl * 3;
            const float4 v = *(const float4*)(x + (((b * F_ + fb + fl) * 3 + k) * N_) + n0 + q * 4);
            int colbase = k * BN + q * 4;
            Xs[colbase + 0][fl] = f2bf(v.x);
            Xs[colbase + 1][fl] = f2bf(v.y);
            Xs[colbase + 2][fl] = f2bf(v.z);
            Xs[colbase + 3][fl] = f2bf(v.w);
        }
        __syncthreads();

        // ---- MFMA: B frags shared across g-tiles and both weights
        short8 bfrag[6];
        #pragma unroll
        for (int ct = 0; ct < 6; ct++)
            bfrag[ct] = *(const short8*)&Xs[ct * 16 + c16][quad * 8];

        #pragma unroll
        for (int wi = 0; wi < 2; wi++) {
            #pragma unroll
            for (int gt = 0; gt < 4; gt++) {
                short8 afrag = *(const short8*)&Ws[wi][wave * 64 + gt * 16 + c16][quad * 8];
                #pragma unroll
                for (int ct = 0; ct < 6; ct++)
                    acc[wi][gt][ct] = __builtin_amdgcn_mfma_f32_16x16x32_bf16(
                        afrag, bfrag[ct], acc[wi][gt][ct], 0, 0, 0);
            }
        }
        __syncthreads();
    }

    // ---- epilogue: lane-local. col = ct*16+c16 -> k = ct>>1, nl = (ct&1)*16+c16
    float m1v[9], m2v[9];
    #pragma unroll
    for (int i = 0; i < 9; i++) { m1v[i] = M1[i]; m2v[i] = M2[i]; }

    #pragma unroll
    for (int gt = 0; gt < 4; gt++) {
        #pragma unroll
        for (int ct0 = 0; ct0 < 2; ct0++) {
            const int n = n0 + ct0 * 16 + c16;
            #pragma unroll
            for (int r = 0; r < 4; r++) {
                const int g = wave * 64 + gt * 16 + quad * 4 + r;
                float c1x = acc[0][gt][ct0 + 0][r];
                float c1y = acc[0][gt][ct0 + 2][r];
                float c1z = acc[0][gt][ct0 + 4][r];
                float c2x = acc[1][gt][ct0 + 0][r];
                float c2y = acc[1][gt][ct0 + 2][r];
                float c2z = acc[1][gt][ct0 + 4][r];
                // d = M1 * c1, e = M2 * c2
                float d0 = m1v[0]*c1x + m1v[1]*c1y + m1v[2]*c1z;
                float d1 = m1v[3]*c1x + m1v[4]*c1y + m1v[5]*c1z;
                float d2 = m1v[6]*c1x + m1v[7]*c1y + m1v[8]*c1z;
                float e0 = m2v[0]*c2x + m2v[1]*c2y + m2v[2]*c2z;
                float e1 = m2v[3]*c2x + m2v[4]*c2y + m2v[5]*c2z;
                float e2 = m2v[6]*c2x + m2v[7]*c2y + m2v[8]*c2z;
                // v = e x d  (lie bracket [hat(e),hat(d)] = hat(e x d))
                float v0 = e1 * d2 - e2 * d1;
                float v1 = e2 * d0 - e0 * d2;
                float v2 = e0 * d1 - e1 * d0;
                const int base = ((b * F_ + g) * 3) * N_ + n;
                out[base + 0 * N_] = x[base + 0 * N_] + v0;
                out[base + 1 * N_] = x[base + 1 * N_] + v1;
                out[base + 2 * N_] = x[base + 2 * N_] + v2;
            }
        }
    }
}

extern "C" void kernel_launch(void* const* d_in, const int* in_sizes, int n_in,
                              void* d_out, int out_size, void* d_ws, size_t ws_size,
                              hipStream_t stream) {
    const float* x  = (const float*)d_in[0];
    const float* M1 = (const float*)d_in[1];
    const float* M2 = (const float*)d_in[2];
    const float* W1 = (const float*)d_in[3];
    const float* W2 = (const float*)d_in[4];
    float* out = (float*)d_out;

    dim3 grid(B_ * (N_ / BN));   // 1024 blocks
    lie_fused_kernel<<<grid, THREADS, 0, stream>>>(x, M1, M2, W1, W2, out);
}

// Round 2
// 237.544 us; speedup vs baseline: 1.4290x; 1.4290x over previous
//
#include <hip/hip_runtime.h>
#include <hip/hip_bf16.h>

#define B_  8
#define F_  256
#define N_  4096
#define BN  32
#define COLS 96       // 3*BN
#define BK  32
#define CHUNKS 8      // F_/BK
#define PAD 40
#define THREADS 512

typedef __attribute__((ext_vector_type(8))) short short8;
typedef __attribute__((ext_vector_type(4))) float f32x4;

__device__ inline unsigned short f2bf(float f) {
    union { float f; unsigned int u; } c; c.f = f;
    unsigned int u = c.u;
    unsigned int r = u + 0x7FFFu + ((u >> 16) & 1u);   // RNE
    return (unsigned short)(r >> 16);
}

// ---- pre-kernel: W1,W2 fp32 -> bf16 Wb[2][256][256] in d_ws ----
__global__ void wconv_kernel(const float* __restrict__ W1,
                             const float* __restrict__ W2,
                             unsigned short* __restrict__ Wb) {
    int t = blockIdx.x * blockDim.x + threadIdx.x;   // 0..16383
    int e = t * 8;                                   // 131072 elems total
    const float* src = (e & 65536) ? W2 : W1;
    int rem = e & 65535;
    float4 a = *(const float4*)(src + rem);
    float4 b = *(const float4*)(src + rem + 4);
    short8 o;
    o[0] = (short)f2bf(a.x); o[1] = (short)f2bf(a.y);
    o[2] = (short)f2bf(a.z); o[3] = (short)f2bf(a.w);
    o[4] = (short)f2bf(b.x); o[5] = (short)f2bf(b.y);
    o[6] = (short)f2bf(b.z); o[7] = (short)f2bf(b.w);
    *(short8*)(Wb + e) = o;
}

// stage one (row,q) cell of the X chunk into swizzled LDS
__device__ inline void stage_elem(const float* __restrict__ xblk, int idx,
                                  unsigned short (*Xs)[PAD]) {
    const int row = idx >> 3;            // 0..95  == fl*3 + k
    const int q   = idx & 7;
    const float4 v = *(const float4*)(xblk + (size_t)row * N_ + q * 4);
    const int fl = row / 3;
    const int k  = row - fl * 3;
    const int g8 = fl >> 3, f7 = fl & 7;
    const int sw = q & 3;                        // == (col>>2)&3 for all 4 cols
    const int off = ((g8 ^ sw) << 3) + f7;
    const int colbase = k * BN + q * 4;
    Xs[colbase + 0][off] = f2bf(v.x);
    Xs[colbase + 1][off] = f2bf(v.y);
    Xs[colbase + 2][off] = f2bf(v.z);
    Xs[colbase + 3][off] = f2bf(v.w);
}

__global__ __launch_bounds__(THREADS, 2) void lie_fused_kernel(
    const float* __restrict__ x, const float* __restrict__ M1,
    const float* __restrict__ M2, const unsigned short* __restrict__ Wb,
    float* __restrict__ out)
{
    __shared__ unsigned short Xs[2][COLS][PAD];   // 15360 B

    const int tid  = threadIdx.x;
    const int wave = tid >> 6;
    const int lane = tid & 63;
    const int c16  = lane & 15;
    const int quad = lane >> 4;
    const int swr  = (c16 >> 2) & 3;

    const int bid   = blockIdx.x;
    const int b     = bid >> 7;
    const int ntile = bid & 127;
    const int n0    = ntile * BN;
    const int g0    = wave * 32;                 // 8 waves x 32 g

    const float* xblk = x + ((size_t)b * F_ * 3) * N_ + n0;

    f32x4 acc[2][2][6];
    #pragma unroll
    for (int wi = 0; wi < 2; wi++)
        #pragma unroll
        for (int gt = 0; gt < 2; gt++)
            #pragma unroll
            for (int ct = 0; ct < 6; ct++)
                acc[wi][gt][ct] = (f32x4)(0.f);

    // prologue: stage chunk 0 into buffer 0
    stage_elem(xblk, tid, Xs[0]);
    if (tid < 256) stage_elem(xblk, 512 + tid, Xs[0]);

    int p = 0;
    for (int ch = 0; ch < CHUNKS; ch++) {
        // A fragments straight from global (bf16 W, L2-resident) — no LDS dep
        short8 af[2][2];
        #pragma unroll
        for (int wi = 0; wi < 2; wi++)
            #pragma unroll
            for (int gt = 0; gt < 2; gt++)
                af[wi][gt] = *(const short8*)(Wb + (wi << 16)
                              + ((g0 + gt * 16 + c16) << 8) + ch * BK + quad * 8);

        __syncthreads();

        short8 bf[6];
        #pragma unroll
        for (int ct = 0; ct < 6; ct++)
            bf[ct] = *(const short8*)&Xs[p][ct * 16 + c16][(quad ^ swr) << 3];

        if (ch < CHUNKS - 1) {
            const float* xn = xblk + (size_t)(ch + 1) * BK * 3 * N_;
            stage_elem(xn, tid, Xs[1 - p]);
            if (tid < 256) stage_elem(xn, 512 + tid, Xs[1 - p]);
        }

        #pragma unroll
        for (int wi = 0; wi < 2; wi++)
            #pragma unroll
            for (int gt = 0; gt < 2; gt++)
                #pragma unroll
                for (int ct = 0; ct < 6; ct++)
                    acc[wi][gt][ct] = __builtin_amdgcn_mfma_f32_16x16x32_bf16(
                        af[wi][gt], bf[ct], acc[wi][gt][ct], 0, 0, 0);
        p ^= 1;
    }

    // ---- epilogue: lane-local rotate + cross + residual add
    float m1v[9], m2v[9];
    #pragma unroll
    for (int i = 0; i < 9; i++) { m1v[i] = M1[i]; m2v[i] = M2[i]; }

    #pragma unroll
    for (int gt = 0; gt < 2; gt++) {
        #pragma unroll
        for (int ct0 = 0; ct0 < 2; ct0++) {
            const int n = n0 + ct0 * 16 + c16;
            #pragma unroll
            for (int r = 0; r < 4; r++) {
                const int g = g0 + gt * 16 + quad * 4 + r;
                float c1x = acc[0][gt][ct0 + 0][r];
                float c1y = acc[0][gt][ct0 + 2][r];
                float c1z = acc[0][gt][ct0 + 4][r];
                float c2x = acc[1][gt][ct0 + 0][r];
                float c2y = acc[1][gt][ct0 + 2][r];
                float c2z = acc[1][gt][ct0 + 4][r];
                float d0 = m1v[0]*c1x + m1v[1]*c1y + m1v[2]*c1z;
                float d1 = m1v[3]*c1x + m1v[4]*c1y + m1v[5]*c1z;
                float d2 = m1v[6]*c1x + m1v[7]*c1y + m1v[8]*c1z;
                float e0 = m2v[0]*c2x + m2v[1]*c2y + m2v[2]*c2z;
                float e1 = m2v[3]*c2x + m2v[4]*c2y + m2v[5]*c2z;
                float e2 = m2v[6]*c2x + m2v[7]*c2y + m2v[8]*c2z;
                float v0 = e1 * d2 - e2 * d1;
                float v1 = e2 * d0 - e0 * d2;
                float v2 = e0 * d1 - e1 * d0;
                const size_t base = ((size_t)(b * F_ + g) * 3) * N_ + n;
                out[base + 0 * N_] = x[base + 0 * N_] + v0;
                out[base + 1 * N_] = x[base + 1 * N_] + v1;
                out[base + 2 * N_] = x[base + 2 * N_] + v2;
            }
        }
    }
}

extern "C" void kernel_launch(void* const* d_in, const int* in_sizes, int n_in,
                              void* d_out, int out_size, void* d_ws, size_t ws_size,
                              hipStream_t stream) {
    const float* x  = (const float*)d_in[0];
    const float* M1 = (const float*)d_in[1];
    const float* M2 = (const float*)d_in[2];
    const float* W1 = (const float*)d_in[3];
    const float* W2 = (const float*)d_in[4];
    float* out = (float*)d_out;
    unsigned short* Wb = (unsigned short*)d_ws;   // 2*256*256*2 = 256 KiB

    wconv_kernel<<<64, 256, 0, stream>>>(W1, W2, Wb);
    lie_fused_kernel<<<B_ * (N_ / BN), THREADS, 0, stream>>>(x, M1, M2, Wb, out);
}

// Round 3
// 221.167 us; speedup vs baseline: 1.5348x; 1.0740x over previous
//
#include <hip/hip_runtime.h>
#include <hip/hip_bf16.h>

#define B_  8
#define F_  256
#define N_  4096
#define BN  32
#define THREADS 512

typedef __attribute__((ext_vector_type(8))) short short8;
typedef __attribute__((ext_vector_type(4))) float f32x4;
typedef __attribute__((ext_vector_type(4))) unsigned short us4;

__device__ inline unsigned short f2bf(float f) {
    union { float f; unsigned int u; } c; c.f = f;
    unsigned int u = c.u;
    unsigned int r = u + 0x7FFFu + ((u >> 16) & 1u);   // RNE
    return (unsigned short)(r >> 16);
}
__device__ inline unsigned int pack2(float a, float b) {
    return (unsigned int)f2bf(a) | ((unsigned int)f2bf(b) << 16);
}
__device__ inline float bf2f(unsigned short h) {
    union { unsigned int u; float f; } c; c.u = ((unsigned int)h) << 16;
    return c.f;
}

// ---- pre-kernel: W1,W2 fp32 -> bf16 Wb[2][256][256] in d_ws ----
__global__ void wconv_kernel(const float* __restrict__ W1,
                             const float* __restrict__ W2,
                             unsigned short* __restrict__ Wb) {
    int t = blockIdx.x * blockDim.x + threadIdx.x;   // 0..16383
    int e = t * 8;
    const float* src = (e & 65536) ? W2 : W1;
    int rem = e & 65535;
    float4 a = *(const float4*)(src + rem);
    float4 b = *(const float4*)(src + rem + 4);
    short8 o;
    o[0] = (short)f2bf(a.x); o[1] = (short)f2bf(a.y);
    o[2] = (short)f2bf(a.z); o[3] = (short)f2bf(a.w);
    o[4] = (short)f2bf(b.x); o[5] = (short)f2bf(b.y);
    o[6] = (short)f2bf(b.z); o[7] = (short)f2bf(b.w);
    *(short8*)(Wb + e) = o;
}

// LDS: 48 tiles (8 f-chunks x 6 col-tiles) x 68 16B-units (64 lanes + 4 pad)
// unit(ch,ct,lane') = (ch*6+ct)*68 + lane' + (lane'>>4); holds 8 bf16 f-values
__global__ __launch_bounds__(THREADS, 4) void lie_fused_kernel(
    const float* __restrict__ x, const float* __restrict__ M1,
    const float* __restrict__ M2, const unsigned short* __restrict__ Wb,
    float* __restrict__ out)
{
    __shared__ unsigned short Xs[48 * 68 * 8];   // 52224 B

    const int tid  = threadIdx.x;
    const int wave = tid >> 6;
    const int lane = tid & 63;
    const int c16  = lane & 15;
    const int quad = lane >> 4;

    const int bid   = blockIdx.x;
    const int gh    = bid & 1;            // g-half: 128 g per block
    const int ntile = (bid >> 1) & 127;
    const int b     = bid >> 8;
    const int n0    = ntile * BN;

    const float* xb = x + (size_t)b * F_ * 3 * N_ + n0;

    // ---- stage entire X tile (256f x 3k x 32n) -> bf16 B-fragments, one burst
    #pragma unroll
    for (int i = 0; i < 6; i++) {
        int pc  = tid + THREADS * i;      // 0..3071
        int q   = pc & 7;                 // n-quad (float4 index)
        int fpl = (pc >> 3) & 7;
        int rr  = pc >> 6;                // 0..47
        int k   = rr % 3;
        int fph = rr / 3;                 // 0..15
        int f0  = (fph * 8 + fpl) * 2;    // even f
        const float* p0 = xb + (size_t)(f0 * 3 + k) * N_ + q * 4;
        float4 va = *(const float4*)p0;            // row f0
        float4 vb = *(const float4*)(p0 + 3 * N_); // row f0+1
        int ch = f0 >> 5;
        int ct = k * 2 + (q >> 2);
        int qp = (f0 & 31) >> 3;                   // f-quad within chunk
        int U0 = (ch * 6 + ct) * 68 + (q & 3) * 4 + 16 * qp + qp;
        unsigned int* dst = (unsigned int*)((char*)Xs + U0 * 16 + (f0 & 7) * 2);
        dst[0]  = pack2(va.x, vb.x);   // lane' = base+0
        dst[4]  = pack2(va.y, vb.y);   // lane' = base+1 (+16B)
        dst[8]  = pack2(va.z, vb.z);
        dst[12] = pack2(va.w, vb.w);
    }

    f32x4 acc[2][6];
    #pragma unroll
    for (int wi = 0; wi < 2; wi++)
        #pragma unroll
        for (int ct = 0; ct < 6; ct++)
            acc[wi][ct] = (f32x4)(0.f);

    const int gRow = gh * 128 + wave * 16 + c16;   // wave owns 16 g rows
    const unsigned short* wb0 = Wb + gRow * 256 + quad * 8;

    __syncthreads();   // the only barrier

    // ---- 8 chunks x 12 MFMA; A-frags from L2 (prefetch depth 1), B from LDS
    short8 Ac0 = *(const short8*)(wb0);
    short8 Ac1 = *(const short8*)(wb0 + 65536);
    #pragma unroll
    for (int ch = 0; ch < 8; ch++) {
        short8 An0, An1;
        if (ch < 7) {
            An0 = *(const short8*)(wb0 + (ch + 1) * 32);
            An1 = *(const short8*)(wb0 + 65536 + (ch + 1) * 32);
        }
        short8 bf[6];
        #pragma unroll
        for (int ct = 0; ct < 6; ct++)
            bf[ct] = *(const short8*)((char*)Xs
                        + (size_t)((ch * 6 + ct) * 68 + lane + quad) * 16);
        #pragma unroll
        for (int ct = 0; ct < 6; ct++)
            acc[0][ct] = __builtin_amdgcn_mfma_f32_16x16x32_bf16(Ac0, bf[ct], acc[0][ct], 0, 0, 0);
        #pragma unroll
        for (int ct = 0; ct < 6; ct++)
            acc[1][ct] = __builtin_amdgcn_mfma_f32_16x16x32_bf16(Ac1, bf[ct], acc[1][ct], 0, 0, 0);
        if (ch < 7) { Ac0 = An0; Ac1 = An1; }
    }

    // ---- epilogue: rotate + cross + residual (residual x read back from LDS)
    float m1v[9], m2v[9];
    #pragma unroll
    for (int i = 0; i < 9; i++) { m1v[i] = M1[i]; m2v[i] = M2[i]; }

    const int gq  = gh * 128 + wave * 16 + quad * 4;  // first of 4 g rows
    const int j0  = (quad & 1) * 4;                   // elem offset in 16B unit
    const int qpp = (gq & 31) >> 3;
    const int chg = gq >> 5;

    #pragma unroll
    for (int ct0 = 0; ct0 < 2; ct0++) {
        const int n = n0 + ct0 * 16 + c16;
        us4 rx[3];
        #pragma unroll
        for (int k = 0; k < 3; k++) {
            int U = (chg * 6 + k * 2 + ct0) * 68 + c16 + 16 * qpp + qpp;
            rx[k] = *(const us4*)((char*)Xs + (size_t)U * 16 + j0 * 2);
        }
        #pragma unroll
        for (int r = 0; r < 4; r++) {
            const int g = gq + r;
            float c1x = acc[0][ct0 + 0][r];
            float c1y = acc[0][ct0 + 2][r];
            float c1z = acc[0][ct0 + 4][r];
            float c2x = acc[1][ct0 + 0][r];
            float c2y = acc[1][ct0 + 2][r];
            float c2z = acc[1][ct0 + 4][r];
            float d0 = m1v[0]*c1x + m1v[1]*c1y + m1v[2]*c1z;
            float d1 = m1v[3]*c1x + m1v[4]*c1y + m1v[5]*c1z;
            float d2 = m1v[6]*c1x + m1v[7]*c1y + m1v[8]*c1z;
            float e0 = m2v[0]*c2x + m2v[1]*c2y + m2v[2]*c2z;
            float e1 = m2v[3]*c2x + m2v[4]*c2y + m2v[5]*c2z;
            float e2 = m2v[6]*c2x + m2v[7]*c2y + m2v[8]*c2z;
            float v0 = e1 * d2 - e2 * d1;
            float v1 = e2 * d0 - e0 * d2;
            float v2 = e0 * d1 - e1 * d0;
            const size_t base = ((size_t)(b * F_ + g) * 3) * N_ + n;
            out[base + 0 * (size_t)N_] = bf2f(rx[0][r]) + v0;
            out[base + 1 * (size_t)N_] = bf2f(rx[1][r]) + v1;
            out[base + 2 * (size_t)N_] = bf2f(rx[2][r]) + v2;
        }
    }
}

extern "C" void kernel_launch(void* const* d_in, const int* in_sizes, int n_in,
                              void* d_out, int out_size, void* d_ws, size_t ws_size,
                              hipStream_t stream) {
    const float* x  = (const float*)d_in[0];
    const float* M1 = (const float*)d_in[1];
    const float* M2 = (const float*)d_in[2];
    const float* W1 = (const float*)d_in[3];
    const float* W2 = (const float*)d_in[4];
    float* out = (float*)d_out;
    unsigned short* Wb = (unsigned short*)d_ws;   // 256 KiB

    wconv_kernel<<<64, 256, 0, stream>>>(W1, W2, Wb);
    lie_fused_kernel<<<2048, THREADS, 0, stream>>>(x, M1, M2, Wb, out);
}

// Round 4
// 212.615 us; speedup vs baseline: 1.5965x; 1.0402x over previous
//
#include <hip/hip_runtime.h>
#include <hip/hip_bf16.h>

#define B_  8
#define F_  256
#define N_  4096
#define BN  16
#define TPB 8            // tiles per block
#define GRID 256
#define THREADS 512
#define TSTRIDE 1088     // (64+4 pad) units * 16 B per (ch,k) sub-tile
#define BUFU (24 * 68)   // uint4 units per buffer

typedef __attribute__((ext_vector_type(8))) short short8;
typedef __attribute__((ext_vector_type(4))) float f32x4;
typedef __attribute__((ext_vector_type(4))) unsigned short us4;

__device__ inline unsigned short f2bf(float f) {
    union { float f; unsigned int u; } c; c.f = f;
    unsigned int u = c.u;
    unsigned int r = u + 0x7FFFu + ((u >> 16) & 1u);   // RNE
    return (unsigned short)(r >> 16);
}
__device__ inline unsigned int pack2(float a, float b) {
    return (unsigned int)f2bf(a) | ((unsigned int)f2bf(b) << 16);
}
__device__ inline float bf2f(unsigned short h) {
    union { unsigned int u; float f; } c; c.u = ((unsigned int)h) << 16;
    return c.f;
}

// ---- pre-kernel: W1,W2 fp32 -> bf16 Wb[2][256][256] in d_ws ----
__global__ void wconv_kernel(const float* __restrict__ W1,
                             const float* __restrict__ W2,
                             unsigned short* __restrict__ Wb) {
    int t = blockIdx.x * blockDim.x + threadIdx.x;   // 0..16383
    int e = t * 8;
    const float* src = (e & 65536) ? W2 : W1;
    int rem = e & 65535;
    float4 a = *(const float4*)(src + rem);
    float4 b = *(const float4*)(src + rem + 4);
    short8 o;
    o[0] = (short)f2bf(a.x); o[1] = (short)f2bf(a.y);
    o[2] = (short)f2bf(a.z); o[3] = (short)f2bf(a.w);
    o[4] = (short)f2bf(b.x); o[5] = (short)f2bf(b.y);
    o[6] = (short)f2bf(b.z); o[7] = (short)f2bf(b.w);
    *(short8*)(Wb + e) = o;
}

__device__ inline void load_tile(const float* __restrict__ xb, int fp, int q,
                                 float4* ra, float4* rb) {
    #pragma unroll
    for (int it = 0; it < 3; it++) {
        const float* p = xb + (size_t)(6 * fp + it) * N_ + q * 4;
        ra[it] = *(const float4*)p;
        rb[it] = *(const float4*)(p + 3 * N_);
    }
}

__device__ inline void write_tile(char* __restrict__ buf, int ch_s, int qw,
                                  int dd, int q, const float4* ra, const float4* rb) {
    #pragma unroll
    for (int it = 0; it < 3; it++) {
        char* tbase = buf + (ch_s * 3 + it) * TSTRIDE + dd * 4;
        const float* fa = (const float*)&ra[it];
        const float* fb = (const float*)&rb[it];
        #pragma unroll
        for (int dn = 0; dn < 4; dn++) {
            int uu = qw * 16 + q * 4 + dn;
            *(unsigned int*)(tbase + (uu + qw) * 16) = pack2(fa[dn], fb[dn]);
        }
    }
}

__global__ __launch_bounds__(THREADS, 2) void lie_fused_kernel(
    const float* __restrict__ x, const float* __restrict__ M1,
    const float* __restrict__ M2, const unsigned short* __restrict__ Wb,
    float* __restrict__ out)
{
    __shared__ uint4 Xs[2][BUFU];   // 2 x 26112 B, B-frag order, pad 1/16 units

    const int tid  = threadIdx.x;
    const int wave = tid >> 6;
    const int lane = tid & 63;
    const int c16  = lane & 15;
    const int quad = lane >> 4;

    // staging decomposition
    const int fp   = tid >> 2;        // 0..127 (f-pair)
    const int q    = tid & 3;         // n float4 index
    const int ch_s = fp >> 4;
    const int fpl  = fp & 15;
    const int qw   = fpl >> 2;
    const int dd   = fpl & 3;

    const int rdoff = (lane + (lane >> 4)) * 16;   // compute-read offset in sub-tile

    const unsigned short* wbase = Wb + (wave * 32 + c16) * 256 + quad * 8;

    float m1v[9], m2v[9];
    #pragma unroll
    for (int i = 0; i < 9; i++) { m1v[i] = M1[i]; m2v[i] = M2[i]; }

    float4 ra[3], rb[3];

    int task = blockIdx.x;
    {
        const float* xb = x + (size_t)(task >> 8) * 768 * N_ + (task & 255) * BN;
        load_tile(xb, fp, q, ra, rb);
    }

    for (int t = 0; t < TPB; t++) {
        char* buf = (char*)Xs[t & 1];

        // consume the loads issued last iteration (or prologue)
        write_tile(buf, ch_s, qw, dd, q, ra, rb);
        __syncthreads();

        const int b  = task >> 8;
        const int nt = task & 255;
        const int next = task + GRID;

        // issue next tile's loads NOW — in flight across MFMA + epilogue
        if (t < TPB - 1) {
            const float* xb = x + (size_t)(next >> 8) * 768 * N_ + (next & 255) * BN;
            load_tile(xb, fp, q, ra, rb);
        }

        f32x4 acc[2][2][3];
        #pragma unroll
        for (int wi = 0; wi < 2; wi++)
            #pragma unroll
            for (int gt = 0; gt < 2; gt++)
                #pragma unroll
                for (int k = 0; k < 3; k++)
                    acc[wi][gt][k] = (f32x4)(0.f);

        short8 a00 = *(const short8*)(wbase);
        short8 a01 = *(const short8*)(wbase + 4096);
        short8 a10 = *(const short8*)(wbase + 65536);
        short8 a11 = *(const short8*)(wbase + 69632);
        #pragma unroll
        for (int ch = 0; ch < 8; ch++) {
            short8 n00, n01, n10, n11;
            if (ch < 7) {
                n00 = *(const short8*)(wbase + (ch + 1) * 32);
                n01 = *(const short8*)(wbase + 4096 + (ch + 1) * 32);
                n10 = *(const short8*)(wbase + 65536 + (ch + 1) * 32);
                n11 = *(const short8*)(wbase + 69632 + (ch + 1) * 32);
            }
            short8 bfr[3];
            #pragma unroll
            for (int k = 0; k < 3; k++)
                bfr[k] = *(const short8*)(buf + (ch * 3 + k) * TSTRIDE + rdoff);
            #pragma unroll
            for (int k = 0; k < 3; k++) {
                acc[0][0][k] = __builtin_amdgcn_mfma_f32_16x16x32_bf16(a00, bfr[k], acc[0][0][k], 0, 0, 0);
                acc[0][1][k] = __builtin_amdgcn_mfma_f32_16x16x32_bf16(a01, bfr[k], acc[0][1][k], 0, 0, 0);
                acc[1][0][k] = __builtin_amdgcn_mfma_f32_16x16x32_bf16(a10, bfr[k], acc[1][0][k], 0, 0, 0);
                acc[1][1][k] = __builtin_amdgcn_mfma_f32_16x16x32_bf16(a11, bfr[k], acc[1][1][k], 0, 0, 0);
            }
            if (ch < 7) { a00 = n00; a01 = n01; a10 = n10; a11 = n11; }
        }

        // epilogue: rotate + cross + residual (x back from LDS)
        float* ob = out + (size_t)b * 768 * N_ + nt * BN + c16;
        #pragma unroll
        for (int gt = 0; gt < 2; gt++) {
            us4 rx[3];
            const int qp = gt * 2 + (quad >> 1);
            #pragma unroll
            for (int k = 0; k < 3; k++) {
                int uu = qp * 16 + c16;
                rx[k] = *(const us4*)(buf + (wave * 3 + k) * TSTRIDE
                           + (uu + qp) * 16 + (quad & 1) * 8);
            }
            #pragma unroll
            for (int r = 0; r < 4; r++) {
                const int g = wave * 32 + gt * 16 + quad * 4 + r;
                float c1x = acc[0][gt][0][r];
                float c1y = acc[0][gt][1][r];
                float c1z = acc[0][gt][2][r];
                float c2x = acc[1][gt][0][r];
                float c2y = acc[1][gt][1][r];
                float c2z = acc[1][gt][2][r];
                float d0 = m1v[0]*c1x + m1v[1]*c1y + m1v[2]*c1z;
                float d1 = m1v[3]*c1x + m1v[4]*c1y + m1v[5]*c1z;
                float d2 = m1v[6]*c1x + m1v[7]*c1y + m1v[8]*c1z;
                float e0 = m2v[0]*c2x + m2v[1]*c2y + m2v[2]*c2z;
                float e1 = m2v[3]*c2x + m2v[4]*c2y + m2v[5]*c2z;
                float e2 = m2v[6]*c2x + m2v[7]*c2y + m2v[8]*c2z;
                float v0 = e1 * d2 - e2 * d1;
                float v1 = e2 * d0 - e0 * d2;
                float v2 = e0 * d1 - e1 * d0;
                ob[(size_t)(g * 3 + 0) * N_] = bf2f(rx[0][r]) + v0;
                ob[(size_t)(g * 3 + 1) * N_] = bf2f(rx[1][r]) + v1;
                ob[(size_t)(g * 3 + 2) * N_] = bf2f(rx[2][r]) + v2;
            }
        }
        task = next;
    }
}

extern "C" void kernel_launch(void* const* d_in, const int* in_sizes, int n_in,
                              void* d_out, int out_size, void* d_ws, size_t ws_size,
                              hipStream_t stream) {
    const float* x  = (const float*)d_in[0];
    const float* M1 = (const float*)d_in[1];
    const float* M2 = (const float*)d_in[2];
    const float* W1 = (const float*)d_in[3];
    const float* W2 = (const float*)d_in[4];
    float* out = (float*)d_out;
    unsigned short* Wb = (unsigned short*)d_ws;   // 256 KiB

    wconv_kernel<<<64, 256, 0, stream>>>(W1, W2, Wb);
    lie_fused_kernel<<<GRID, THREADS, 0, stream>>>(x, M1, M2, Wb, out);
}